// Round 10
// baseline (180.592 us; speedup 1.0000x reference)
//
#include <hip/hip_runtime.h>

// DCT2D, 8 threads per 8x8 block, single lane-transpose, 2 consecutive blocks
// per 8-lane group per iteration (round-7 structure, best=76.7us), with
// STREAMING STORES: global_store_dwordx4 with sc0 sc1 nt aux bits so output
// does NOT allocate in L2/Infinity-Cache. Input (201 MB) then fits fully in
// the 256 MB L3 across graph replays -> FETCH_SIZE should drop 98MB -> ~0.
//   lane r loads column r:  o[x] = X[b][x][r]
//   pass1 (local):  t[u]   = sum_x cs[x][u] * (o[x]-128)
//   -- one lane transpose --  lane r holds T[r][y]
//   pass2 (local):  res[v] = sum_y T[r][y] * cs[y][v]   -> out row r
//   coalesced 32B streaming row stores.
// cs[a][b] = c[a][b]*alpha[b]*0.5, recovered exactly from inputs:
//   c[a][b]      = dct_tensor[a,0,b,0]   (c[0][0]==1)
//   alpha[b]*0.5 = scale[b,0] * 2*sqrt(2)

typedef float vfloat4 __attribute__((ext_vector_type(4)));

__device__ __forceinline__ float uniformf(float v)
{
    return __int_as_float(__builtin_amdgcn_readfirstlane(__float_as_int(v)));
}

// streaming store: bypass/no-allocate L2 + MALL (sc0 sc1 nt)
__device__ __forceinline__ void stream_store4(float* p, vfloat4 v)
{
    asm volatile("global_store_dwordx4 %0, %1, off sc0 sc1 nt"
                 :: "v"(p), "v"(v) : "memory");
}

__device__ __forceinline__ void xpose8(float a[8], bool h1, bool h2, bool h4)
{
#pragma unroll
    for (int j = 0; j < 8; j += 2) {
        const int k = j + 1;
        float fj = __shfl_xor(a[k], 1);
        float fk = __shfl_xor(a[j], 1);
        float nj = h1 ? fj : a[j];
        float nk = h1 ? a[k] : fk;
        a[j] = nj; a[k] = nk;
    }
#pragma unroll
    for (int jj = 0; jj < 8; jj += 4) {
#pragma unroll
        for (int j0 = 0; j0 < 2; ++j0) {
            const int j = jj + j0, k = j + 2;
            float fj = __shfl_xor(a[k], 2);
            float fk = __shfl_xor(a[j], 2);
            float nj = h2 ? fj : a[j];
            float nk = h2 ? a[k] : fk;
            a[j] = nj; a[k] = nk;
        }
    }
#pragma unroll
    for (int j = 0; j < 4; ++j) {
        const int k = j + 4;
        float fj = __shfl_xor(a[k], 4);
        float fk = __shfl_xor(a[j], 4);
        float nj = h4 ? fj : a[j];
        float nk = h4 ? a[k] : fk;
        a[j] = nj; a[k] = nk;
    }
}

// column data o[8] (already -128'd) -> output row `lane` res[8]
__device__ __forceinline__ void dct_block(const float o[8], float res[8],
                                          const float cs[8][8],
                                          bool h1, bool h2, bool h4)
{
    float t[8];
#pragma unroll
    for (int u = 0; u < 8; ++u) {
        float s = 0.0f;
#pragma unroll
        for (int xx = 0; xx < 8; ++xx) s = fmaf(o[xx], cs[xx][u], s);
        t[u] = s;
    }
    xpose8(t, h1, h2, h4);
#pragma unroll
    for (int v = 0; v < 8; ++v) {
        float s = 0.0f;
#pragma unroll
        for (int y = 0; y < 8; ++y) s = fmaf(t[y], cs[y][v], s);
        res[v] = s;
    }
}

__global__ __launch_bounds__(256) void dct2d_kernel(
    const float* __restrict__ x,
    const float* __restrict__ dct,     // [8,8,8,8] = c[x,u]*c[y,v]
    const float* __restrict__ scale,   // [8,8]
    float* __restrict__ out,
    int nblocks)
{
    const int tid  = blockIdx.x * blockDim.x + threadIdx.x;
    const int lane = tid & 7;                    // column index within 8x8 block
    const int g    = tid >> 3;                   // 8-lane group id
    const int ngroups = (gridDim.x * blockDim.x) >> 3;

    // wave-uniform folded constant matrix, forced to SGPRs
    float cs[8][8];
#pragma unroll
    for (int b = 0; b < 8; ++b) {
        const float a05 = scale[b * 8] * 2.8284271247461903f;  // alpha[b]*0.5
#pragma unroll
        for (int a = 0; a < 8; ++a)
            cs[a][b] = uniformf(dct[a * 512 + b * 8] * a05);   // c[a][b]*a05
    }

    const bool h1 = (lane & 1) != 0;
    const bool h2 = (lane & 2) != 0;
    const bool h4 = (lane & 4) != 0;

    int b0 = 2 * g;
    for (; b0 + 1 < nblocks; b0 += 2 * ngroups) {
        const float* p = x + (size_t)b0 * 64 + lane;
        // hoist all 16 column loads (2 consecutive blocks) before any compute
        float oA[8], oB[8];
#pragma unroll
        for (int xx = 0; xx < 8; ++xx) oA[xx] = p[xx * 8];
#pragma unroll
        for (int xx = 0; xx < 8; ++xx) oB[xx] = p[64 + xx * 8];
#pragma unroll
        for (int xx = 0; xx < 8; ++xx) { oA[xx] -= 128.0f; oB[xx] -= 128.0f; }

        float rA[8], rB[8];
        dct_block(oA, rA, cs, h1, h2, h4);
        dct_block(oB, rB, cs, h1, h2, h4);

        float* op = out + (size_t)b0 * 64 + lane * 8;
        vfloat4 sA0 = { rA[0], rA[1], rA[2], rA[3] };
        vfloat4 sA1 = { rA[4], rA[5], rA[6], rA[7] };
        vfloat4 sB0 = { rB[0], rB[1], rB[2], rB[3] };
        vfloat4 sB1 = { rB[4], rB[5], rB[6], rB[7] };
        stream_store4(op,      sA0);
        stream_store4(op + 4,  sA1);
        stream_store4(op + 64, sB0);
        stream_store4(op + 68, sB1);
    }
    // tail: at most one block left (not hit with 786432 blocks / 131072 per sweep)
    if (b0 < nblocks) {
        const float* p = x + (size_t)b0 * 64 + lane;
        float o[8];
#pragma unroll
        for (int xx = 0; xx < 8; ++xx) o[xx] = p[xx * 8] - 128.0f;
        float r[8];
        dct_block(o, r, cs, h1, h2, h4);
        float* op = out + (size_t)b0 * 64 + lane * 8;
        vfloat4 s0 = { r[0], r[1], r[2], r[3] };
        vfloat4 s1 = { r[4], r[5], r[6], r[7] };
        stream_store4(op,     s0);
        stream_store4(op + 4, s1);
    }
}

extern "C" void kernel_launch(void* const* d_in, const int* in_sizes, int n_in,
                              void* d_out, int out_size, void* d_ws, size_t ws_size,
                              hipStream_t stream)
{
    const float* x     = (const float*)d_in[0];
    const float* dct   = (const float*)d_in[1];
    const float* scale = (const float*)d_in[2];
    float* out = (float*)d_out;

    int nblocks = in_sizes[0] / 64;   // number of 8x8 tiles (262144*3)
    int block = 256;
    int grid  = 2048;                 // 65536 groups; 786432/(2*65536)=6 iters exact

    dct2d_kernel<<<grid, block, 0, stream>>>(x, dct, scale, out, nblocks);
}

// Round 11
// 84.654 us; speedup vs baseline: 2.1333x; 2.1333x over previous
//
#include <hip/hip_runtime.h>

// DCT2D, 8 threads per 8x8 block, single lane-transpose, FOUR consecutive
// blocks per 8-lane group per iteration: 32 hoisted column loads (8 KB/wave
// in flight) -> compiler's counted-vmcnt overlap of compute(A) with loads(C,D).
// Round-7 structure otherwise (builtin nontemporal stores — sc0/sc1 asm bypass
// proven 2.4x WORSE in r10: skipping L2 kills partial-line write combining).
//   lane r loads column r:  o[x] = X[b][x][r]
//   pass1 (local):  t[u]   = sum_x cs[x][u] * (o[x]-128)
//   -- one lane transpose --  lane r holds T[r][y]
//   pass2 (local):  res[v] = sum_y T[r][y] * cs[y][v]   -> out row r
//   coalesced 32B nontemporal row stores (WRITE_SIZE ideal at 210 MB).
// cs[a][b] = c[a][b]*alpha[b]*0.5, recovered exactly from inputs:
//   c[a][b]      = dct_tensor[a,0,b,0]   (c[0][0]==1)
//   alpha[b]*0.5 = scale[b,0] * 2*sqrt(2)

typedef float vfloat4 __attribute__((ext_vector_type(4)));

__device__ __forceinline__ float uniformf(float v)
{
    return __int_as_float(__builtin_amdgcn_readfirstlane(__float_as_int(v)));
}

__device__ __forceinline__ void xpose8(float a[8], bool h1, bool h2, bool h4)
{
#pragma unroll
    for (int j = 0; j < 8; j += 2) {
        const int k = j + 1;
        float fj = __shfl_xor(a[k], 1);
        float fk = __shfl_xor(a[j], 1);
        float nj = h1 ? fj : a[j];
        float nk = h1 ? a[k] : fk;
        a[j] = nj; a[k] = nk;
    }
#pragma unroll
    for (int jj = 0; jj < 8; jj += 4) {
#pragma unroll
        for (int j0 = 0; j0 < 2; ++j0) {
            const int j = jj + j0, k = j + 2;
            float fj = __shfl_xor(a[k], 2);
            float fk = __shfl_xor(a[j], 2);
            float nj = h2 ? fj : a[j];
            float nk = h2 ? a[k] : fk;
            a[j] = nj; a[k] = nk;
        }
    }
#pragma unroll
    for (int j = 0; j < 4; ++j) {
        const int k = j + 4;
        float fj = __shfl_xor(a[k], 4);
        float fk = __shfl_xor(a[j], 4);
        float nj = h4 ? fj : a[j];
        float nk = h4 ? a[k] : fk;
        a[j] = nj; a[k] = nk;
    }
}

// column data o[8] (already -128'd) -> output row `lane` res[8]
__device__ __forceinline__ void dct_block(const float o[8], float res[8],
                                          const float cs[8][8],
                                          bool h1, bool h2, bool h4)
{
    float t[8];
#pragma unroll
    for (int u = 0; u < 8; ++u) {
        float s = 0.0f;
#pragma unroll
        for (int xx = 0; xx < 8; ++xx) s = fmaf(o[xx], cs[xx][u], s);
        t[u] = s;
    }
    xpose8(t, h1, h2, h4);
#pragma unroll
    for (int v = 0; v < 8; ++v) {
        float s = 0.0f;
#pragma unroll
        for (int y = 0; y < 8; ++y) s = fmaf(t[y], cs[y][v], s);
        res[v] = s;
    }
}

// one block: subtract 128, DCT, nontemporal row store
__device__ __forceinline__ void finish_block(const float oraw[8], float* op,
                                             const float cs[8][8],
                                             bool h1, bool h2, bool h4)
{
    float o[8];
#pragma unroll
    for (int xx = 0; xx < 8; ++xx) o[xx] = oraw[xx] - 128.0f;
    float r[8];
    dct_block(o, r, cs, h1, h2, h4);
    vfloat4 s0 = { r[0], r[1], r[2], r[3] };
    vfloat4 s1 = { r[4], r[5], r[6], r[7] };
    __builtin_nontemporal_store(s0, reinterpret_cast<vfloat4*>(op));
    __builtin_nontemporal_store(s1, reinterpret_cast<vfloat4*>(op + 4));
}

__global__ __launch_bounds__(256) void dct2d_kernel(
    const float* __restrict__ x,
    const float* __restrict__ dct,     // [8,8,8,8] = c[x,u]*c[y,v]
    const float* __restrict__ scale,   // [8,8]
    float* __restrict__ out,
    int nblocks)
{
    const int tid  = blockIdx.x * blockDim.x + threadIdx.x;
    const int lane = tid & 7;                    // column index within 8x8 block
    const int g    = tid >> 3;                   // 8-lane group id
    const int ngroups = (gridDim.x * blockDim.x) >> 3;

    // wave-uniform folded constant matrix, forced to SGPRs
    float cs[8][8];
#pragma unroll
    for (int b = 0; b < 8; ++b) {
        const float a05 = scale[b * 8] * 2.8284271247461903f;  // alpha[b]*0.5
#pragma unroll
        for (int a = 0; a < 8; ++a)
            cs[a][b] = uniformf(dct[a * 512 + b * 8] * a05);   // c[a][b]*a05
    }

    const bool h1 = (lane & 1) != 0;
    const bool h2 = (lane & 2) != 0;
    const bool h4 = (lane & 4) != 0;

    int b0 = 4 * g;
    // main: four consecutive blocks per iteration, all 32 loads hoisted
    for (; b0 + 3 < nblocks; b0 += 4 * ngroups) {
        const float* p = x + (size_t)b0 * 64 + lane;
        float oA[8], oB[8], oC[8], oD[8];
#pragma unroll
        for (int xx = 0; xx < 8; ++xx) oA[xx] = p[xx * 8];
#pragma unroll
        for (int xx = 0; xx < 8; ++xx) oB[xx] = p[64 + xx * 8];
#pragma unroll
        for (int xx = 0; xx < 8; ++xx) oC[xx] = p[128 + xx * 8];
#pragma unroll
        for (int xx = 0; xx < 8; ++xx) oD[xx] = p[192 + xx * 8];

        float* op = out + (size_t)b0 * 64 + lane * 8;
        finish_block(oA, op,       cs, h1, h2, h4);
        finish_block(oB, op + 64,  cs, h1, h2, h4);
        finish_block(oC, op + 128, cs, h1, h2, h4);
        finish_block(oD, op + 192, cs, h1, h2, h4);
    }
    // tail: up to 3 blocks left (not hit at 786432 = 4*65536*3)
    for (; b0 < nblocks; ++b0) {
        const float* p = x + (size_t)b0 * 64 + lane;
        float o[8];
#pragma unroll
        for (int xx = 0; xx < 8; ++xx) o[xx] = p[xx * 8];
        finish_block(o, out + (size_t)b0 * 64 + lane * 8, cs, h1, h2, h4);
    }
}

extern "C" void kernel_launch(void* const* d_in, const int* in_sizes, int n_in,
                              void* d_out, int out_size, void* d_ws, size_t ws_size,
                              hipStream_t stream)
{
    const float* x     = (const float*)d_in[0];
    const float* dct   = (const float*)d_in[1];
    const float* scale = (const float*)d_in[2];
    float* out = (float*)d_out;

    int nblocks = in_sizes[0] / 64;   // number of 8x8 tiles (262144*3)
    int block = 256;
    int grid  = 2048;                 // 65536 groups; 786432/(4*65536)=3 iters exact

    dct2d_kernel<<<grid, block, 0, stream>>>(x, dct, scale, out, nblocks);
}

// Round 12
// 76.769 us; speedup vs baseline: 2.3524x; 1.1027x over previous
//
#include <hip/hip_runtime.h>

// DCT2D — FINAL (round-7 structure, best measured: 76.7 us, 5.36 TB/s eff,
// 85% of D2D copy ceiling; all pipes idle, byte counts compulsory-minimal).
//
// Structure: 8 threads per 8x8 block, 2 consecutive blocks per 8-lane group
// per iteration (wave = 4 KB contiguous read burst + 4 KB write burst).
//   lane r loads column r:  o[x] = X[b][x][r]        (16 hoisted loads)
//   pass1 (local):  t[u]   = sum_x cs[x][u] * (o[x]-128)
//   -- ONE lane transpose (xor-shuffle butterfly) --  lane r holds T[r][y]
//   pass2 (local):  res[v] = sum_y T[r][y] * cs[y][v]   -> out row r
//   coalesced 32B nontemporal row stores.
//
// Probe matrix (what NOT to change — each measured as a regression):
//   - distant-stream ILP x2 (r5, -7%), reg double-buffer pipeline (r8, -4%)
//   - LDS-staged fully-coalesced reads (r9, -9%): fragmentation NOT the limit
//   - sc0/sc1/nt store bypass (r10, -135%): L2 partial-line write combining
//     is mandatory; builtin nontemporal (NT-bit only) is the right store
//   - x4 consecutive burst (r11, -10%): VGPR 48 -> occupancy cliff
//
// cs[a][b] = c[a][b]*alpha[b]*0.5, recovered exactly from inputs:
//   c[a][b]      = dct_tensor[a,0,b,0]   (c[0][0]==1)
//   alpha[b]*0.5 = scale[b,0] * 2*sqrt(2)
// cs wave-uniform -> SGPRs via readfirstlane (VGPR=32, 8 waves/SIMD).

typedef float vfloat4 __attribute__((ext_vector_type(4)));

__device__ __forceinline__ float uniformf(float v)
{
    return __int_as_float(__builtin_amdgcn_readfirstlane(__float_as_int(v)));
}

__device__ __forceinline__ void xpose8(float a[8], bool h1, bool h2, bool h4)
{
#pragma unroll
    for (int j = 0; j < 8; j += 2) {
        const int k = j + 1;
        float fj = __shfl_xor(a[k], 1);
        float fk = __shfl_xor(a[j], 1);
        float nj = h1 ? fj : a[j];
        float nk = h1 ? a[k] : fk;
        a[j] = nj; a[k] = nk;
    }
#pragma unroll
    for (int jj = 0; jj < 8; jj += 4) {
#pragma unroll
        for (int j0 = 0; j0 < 2; ++j0) {
            const int j = jj + j0, k = j + 2;
            float fj = __shfl_xor(a[k], 2);
            float fk = __shfl_xor(a[j], 2);
            float nj = h2 ? fj : a[j];
            float nk = h2 ? a[k] : fk;
            a[j] = nj; a[k] = nk;
        }
    }
#pragma unroll
    for (int j = 0; j < 4; ++j) {
        const int k = j + 4;
        float fj = __shfl_xor(a[k], 4);
        float fk = __shfl_xor(a[j], 4);
        float nj = h4 ? fj : a[j];
        float nk = h4 ? a[k] : fk;
        a[j] = nj; a[k] = nk;
    }
}

// column data o[8] (already -128'd) -> output row `lane` res[8]
__device__ __forceinline__ void dct_block(const float o[8], float res[8],
                                          const float cs[8][8],
                                          bool h1, bool h2, bool h4)
{
    float t[8];
#pragma unroll
    for (int u = 0; u < 8; ++u) {
        float s = 0.0f;
#pragma unroll
        for (int xx = 0; xx < 8; ++xx) s = fmaf(o[xx], cs[xx][u], s);
        t[u] = s;
    }
    xpose8(t, h1, h2, h4);
#pragma unroll
    for (int v = 0; v < 8; ++v) {
        float s = 0.0f;
#pragma unroll
        for (int y = 0; y < 8; ++y) s = fmaf(t[y], cs[y][v], s);
        res[v] = s;
    }
}

__global__ __launch_bounds__(256) void dct2d_kernel(
    const float* __restrict__ x,
    const float* __restrict__ dct,     // [8,8,8,8] = c[x,u]*c[y,v]
    const float* __restrict__ scale,   // [8,8]
    float* __restrict__ out,
    int nblocks)
{
    const int tid  = blockIdx.x * blockDim.x + threadIdx.x;
    const int lane = tid & 7;                    // column index within 8x8 block
    const int g    = tid >> 3;                   // 8-lane group id
    const int ngroups = (gridDim.x * blockDim.x) >> 3;

    // wave-uniform folded constant matrix, forced to SGPRs
    float cs[8][8];
#pragma unroll
    for (int b = 0; b < 8; ++b) {
        const float a05 = scale[b * 8] * 2.8284271247461903f;  // alpha[b]*0.5
#pragma unroll
        for (int a = 0; a < 8; ++a)
            cs[a][b] = uniformf(dct[a * 512 + b * 8] * a05);   // c[a][b]*a05
    }

    const bool h1 = (lane & 1) != 0;
    const bool h2 = (lane & 2) != 0;
    const bool h4 = (lane & 4) != 0;

    int b0 = 2 * g;
    for (; b0 + 1 < nblocks; b0 += 2 * ngroups) {
        const float* p = x + (size_t)b0 * 64 + lane;
        // hoist all 16 column loads (2 consecutive blocks) before any compute
        float oA[8], oB[8];
#pragma unroll
        for (int xx = 0; xx < 8; ++xx) oA[xx] = p[xx * 8];
#pragma unroll
        for (int xx = 0; xx < 8; ++xx) oB[xx] = p[64 + xx * 8];
#pragma unroll
        for (int xx = 0; xx < 8; ++xx) { oA[xx] -= 128.0f; oB[xx] -= 128.0f; }

        float rA[8], rB[8];
        dct_block(oA, rA, cs, h1, h2, h4);
        dct_block(oB, rB, cs, h1, h2, h4);

        float* op = out + (size_t)b0 * 64 + lane * 8;
        vfloat4 sA0 = { rA[0], rA[1], rA[2], rA[3] };
        vfloat4 sA1 = { rA[4], rA[5], rA[6], rA[7] };
        vfloat4 sB0 = { rB[0], rB[1], rB[2], rB[3] };
        vfloat4 sB1 = { rB[4], rB[5], rB[6], rB[7] };
        __builtin_nontemporal_store(sA0, reinterpret_cast<vfloat4*>(op));
        __builtin_nontemporal_store(sA1, reinterpret_cast<vfloat4*>(op + 4));
        __builtin_nontemporal_store(sB0, reinterpret_cast<vfloat4*>(op + 64));
        __builtin_nontemporal_store(sB1, reinterpret_cast<vfloat4*>(op + 68));
    }
    // tail: at most one block left (not hit with 786432 blocks / 131072 per sweep)
    if (b0 < nblocks) {
        const float* p = x + (size_t)b0 * 64 + lane;
        float o[8];
#pragma unroll
        for (int xx = 0; xx < 8; ++xx) o[xx] = p[xx * 8] - 128.0f;
        float r[8];
        dct_block(o, r, cs, h1, h2, h4);
        float* op = out + (size_t)b0 * 64 + lane * 8;
        vfloat4 s0 = { r[0], r[1], r[2], r[3] };
        vfloat4 s1 = { r[4], r[5], r[6], r[7] };
        __builtin_nontemporal_store(s0, reinterpret_cast<vfloat4*>(op));
        __builtin_nontemporal_store(s1, reinterpret_cast<vfloat4*>(op + 4));
    }
}

extern "C" void kernel_launch(void* const* d_in, const int* in_sizes, int n_in,
                              void* d_out, int out_size, void* d_ws, size_t ws_size,
                              hipStream_t stream)
{
    const float* x     = (const float*)d_in[0];
    const float* dct   = (const float*)d_in[1];
    const float* scale = (const float*)d_in[2];
    float* out = (float*)d_out;

    int nblocks = in_sizes[0] / 64;   // number of 8x8 tiles (262144*3)
    int block = 256;
    int grid  = 2048;                 // 65536 groups; 786432/(2*65536)=6 iters exact

    dct2d_kernel<<<grid, block, 0, stream>>>(x, dct, scale, out, nblocks);
}